// Round 1
// baseline (1224.602 us; speedup 1.0000x reference)
//
#include <hip/hip_runtime.h>
#include <math.h>

#define LN    524288        // signal length, 2^19
#define N1    512           // first-FFT length (k1 fast in freq index)
#define N2    1024          // second-FFT length
#define NCH   129
#define DSR   80            // downsample rate
#define NOUT  6553          // number of output frames per channel
#define OB    128           // outputs per IIR block
#define NBLK  52            // ceil(NOUT/OB)
#define NPAIR 65            // ceil(129/2) channel pairs
#define KTAIL 48            // LN - NOUT*DSR

typedef float2 cfloat;

__device__ __forceinline__ float2 cmulf(float2 a, float2 b) {
    return make_float2(a.x*b.x - a.y*b.y, a.x*b.y + a.y*b.x);
}

// ---------------- pack real x into complex buffer ----------------
__global__ void pack_x(const float* __restrict__ x, float2* __restrict__ dst) {
    int i = blockIdx.x * 256 + threadIdx.x;
    dst[i] = make_float2(x[i], 0.f);
}

// ---------------- tiled complex transpose: src[R x C] -> dst[C x R] ----------------
// grid: (C/32, R/32, batch), block (32,8)
__global__ void transpose_c(const float2* __restrict__ src, float2* __restrict__ dst,
                            int R, int Cc) {
    __shared__ float2 tile[32][33];
    size_t boff = (size_t)blockIdx.z * LN;
    src += boff; dst += boff;
    int x  = blockIdx.x * 32 + threadIdx.x;
    int y0 = blockIdx.y * 32 + threadIdx.y;
#pragma unroll
    for (int i = 0; i < 32; i += 8)
        tile[threadIdx.y + i][threadIdx.x] = src[(size_t)(y0 + i) * Cc + x];
    __syncthreads();
    int xo  = blockIdx.y * 32 + threadIdx.x;
    int yo0 = blockIdx.x * 32 + threadIdx.y;
#pragma unroll
    for (int i = 0; i < 32; i += 8)
        dst[(size_t)(yo0 + i) * R + xo] = tile[threadIdx.x][threadIdx.y + i];
}

// ---------------- LDS Stockham radix-2 row FFT, natural in/out ----------------
// One row of length M per workgroup. Optional post-twiddle e^{SIGN*2pi*i*row*col/LN}.
template<int M, int SIGN, int TW>
__global__ __launch_bounds__(256) void fft_rows(const float2* __restrict__ src,
                                                float2* __restrict__ dst,
                                                int rows_per_batch) {
    __shared__ float2 ping[M];
    __shared__ float2 pong[M];
    size_t rowg = blockIdx.x;
    const float2* srow = src + rowg * M;
    float2* drow = dst + rowg * M;
    int row = (int)(rowg % (size_t)rows_per_batch);
    int t = threadIdx.x;
    for (int i = t; i < M; i += 256) ping[i] = srow[i];
    __syncthreads();
    float2* a = ping;
    float2* b = pong;
    for (int Ns = 1; Ns < M; Ns <<= 1) {
        for (int j = t; j < M/2; j += 256) {
            int jm = j & (Ns - 1);
            float2 v0 = a[j];
            float2 v1 = a[j + M/2];
            // twiddle e^{i * SIGN * pi * jm / Ns}
            float ang = (float)SIGN * 3.14159265358979323846f * ((float)jm / (float)Ns);
            float s, c;
            __sincosf(ang, &s, &c);
            float2 w = make_float2(v1.x*c - v1.y*s, v1.x*s + v1.y*c);
            int d0 = ((j & ~(Ns - 1)) << 1) | jm;
            b[d0]      = make_float2(v0.x + w.x, v0.y + w.y);
            b[d0 + Ns] = make_float2(v0.x - w.x, v0.y - w.y);
        }
        __syncthreads();
        float2* tmp = a; a = b; b = tmp;
    }
    if (TW) {
        const float c2pi = 6.28318530717958647692f / (float)LN;
        for (int i = t; i < M; i += 256) {
            float2 v = a[i];
            unsigned prod = ((unsigned)row * (unsigned)i) & (unsigned)(LN - 1);
            float ang = (float)SIGN * c2pi * (float)prod;
            float s, c;
            __sincosf(ang, &s, &c);
            drow[i] = make_float2(v.x*c - v.y*s, v.x*s + v.y*c);
        }
    } else {
        for (int i = t; i < M; i += 256) drow[i] = a[i];
    }
}

// ---------------- build paired Hermitian spectra W = Herm(Ya) + i*Herm(Yb) ----------------
// Ya = Hs[2p]*X, Yb = Hs[2p+1]*X. Each thread handles k and L-k (Hs read exactly once).
__global__ void build_w(const float* __restrict__ Hr, const float* __restrict__ Hi,
                        const float2* __restrict__ X, float2* __restrict__ W,
                        int pair0, int npairs) {
    size_t tid = (size_t)blockIdx.x * 256 + threadIdx.x;
    const size_t half = LN / 2;
    int pl = (int)(tid / half);
    if (pl >= npairs) return;
    unsigned k = (unsigned)(tid % half);
    int p = pair0 + pl;
    int ca = 2*p, cb = 2*p + 1;
    const float* Har = Hr + (size_t)ca * LN;
    const float* Hai = Hi + (size_t)ca * LN;
    const bool hasB = (cb < NCH);
    const float* Hbr = hasB ? (Hr + (size_t)cb * LN) : nullptr;
    const float* Hbi = hasB ? (Hi + (size_t)cb * LN) : nullptr;
    float2* Wp = W + (size_t)pl * LN;
    if (k == 0) {
        // self-paired bins k = 0 and k = L/2: Herm part is (Re, 0)
        for (int kk = 0; kk < 2; kk++) {
            unsigned idx = kk ? (unsigned)half : 0u;
            float2 Xv = X[idx];
            float2 Ya = cmulf(make_float2(Har[idx], Hai[idx]), Xv);
            float br = 0.f;
            if (hasB) { float2 Yb = cmulf(make_float2(Hbr[idx], Hbi[idx]), Xv); br = Yb.x; }
            Wp[idx] = make_float2(Ya.x, br);
        }
        return;
    }
    unsigned kL = (unsigned)LN - k;
    float2 X1 = X[k], X2 = X[kL];
    float2 a1 = cmulf(make_float2(Har[k],  Hai[k]),  X1);
    float2 a2 = cmulf(make_float2(Har[kL], Hai[kL]), X2);
    float2 b1 = make_float2(0.f, 0.f), b2 = make_float2(0.f, 0.f);
    if (hasB) {
        b1 = cmulf(make_float2(Hbr[k],  Hbi[k]),  X1);
        b2 = cmulf(make_float2(Hbr[kL], Hbi[kL]), X2);
    }
    float yar = 0.5f*(a1.x + a2.x), yai = 0.5f*(a1.y - a2.y);
    float ybr = 0.5f*(b1.x + b2.x), ybi = 0.5f*(b1.y - b2.y);
    Wp[k]  = make_float2(yar - ybi, yai + ybr);
    float yar2 = 0.5f*(a2.x + a1.x), yai2 = 0.5f*(a2.y - a1.y);
    float ybr2 = 0.5f*(b2.x + b1.x), ybi2 = 0.5f*(b2.y - b1.y);
    Wp[kL] = make_float2(yar2 - ybi2, yai2 + ybr2);
}

// ---------------- final transpose of IFFT + 1/L scale + power-law, write 2 channels ----------------
// src: per-pair matrix M4[512 x 1024]; natural time index n = r + 512*c.
__global__ void ifft_finish(const float2* __restrict__ src, float* __restrict__ comp,
                            const float* __restrict__ alpha_comp, int pair0) {
    __shared__ float2 tile[32][33];
    int pl = blockIdx.z;
    int p = pair0 + pl;
    int ca = 2*p, cb = 2*p + 1;
    const float2* s = src + (size_t)pl * LN;
    int x  = blockIdx.x * 32 + threadIdx.x;   // col (k2) in [0,1024)
    int y0 = blockIdx.y * 32 + threadIdx.y;   // row (k1) in [0,512)
#pragma unroll
    for (int i = 0; i < 32; i += 8)
        tile[threadIdx.y + i][threadIdx.x] = s[(size_t)(y0 + i) * N2 + x];
    __syncthreads();
    float aa = alpha_comp[ca];
    float ab = (cb < NCH) ? alpha_comp[cb] : 1.f;
    const float invL = 1.f / (float)LN;
    int xo  = blockIdx.y * 32 + threadIdx.x;  // r
    int yo0 = blockIdx.x * 32 + threadIdx.y;  // c
#pragma unroll
    for (int i = 0; i < 32; i += 8) {
        int yo = yo0 + i;
        float2 v = tile[threadIdx.x][threadIdx.y + i];
        size_t n = (size_t)yo * N1 + xo;
        float ra = v.x * invL;
        float rb = v.y * invL;
        comp[(size_t)ca * LN + n] = copysignf(powf(fabsf(ra), aa), ra);
        if (cb < NCH)
            comp[(size_t)cb * LN + n] = copysignf(powf(fabsf(rb), ab), rb);
    }
}

// ---------------- leaky IIR part 1: per-block 80-tap partials + affine scan ----------------
// grid: (NBLK, NCH), block 256
__global__ __launch_bounds__(256) void iir_part1(
    const float* __restrict__ comp, const float* __restrict__ alpha_leak,
    const float* __restrict__ li_kernel, float* __restrict__ out,
    float* __restrict__ carryOut) {
    __shared__ float win[OB * DSR];   // 10240 lin samples
    __shared__ float apow[DSR];
    __shared__ float sv[OB];
    __shared__ float sg[OB];
    int blk = blockIdx.x;
    int c = blockIdx.y;
    int t = threadIdx.x;
    float alpha = alpha_leak[0];
    float k0 = li_kernel[0], k1 = li_kernel[1];
    if (t < DSR) apow[t] = powf(alpha, (float)t);
    int base = blk * (OB * DSR);
    const int cap = NOUT * DSR;   // 524240
    const float* c0 = comp + (size_t)c * LN;
    const float* c1 = (c + 1 < NCH) ? comp + (size_t)(c + 1) * LN : nullptr;
    for (int i = t; i < OB * DSR; i += 256) {
        int g = base + i;
        float v = 0.f;
        if (g < cap) {
            float u0 = c0[g];
            float u1 = c1 ? c1[g] : 0.f;
            v = k0 * u0 + k1 * u1;
            v = v > 0.f ? v : 0.f;
        }
        win[i] = v;
    }
    __syncthreads();
    int nact = NOUT - blk * OB; if (nact > OB) nact = OB;
    float beta = powf(alpha, (float)DSR);
    if (t < OB) {
        int o = t;
        int baseo = o * DSR + (DSR - 1);
        float P = 0.f;
        int rot = o & 31;                 // skew start to spread LDS banks
        for (int jj = 0; jj < DSR; jj++) {
            int j = jj + rot; if (j >= DSR) j -= DSR;
            P += apow[j] * win[baseo - j];
        }
        sv[o] = P; sg[o] = beta;
    }
    __syncthreads();
    // Hillis-Steele scan of affine maps: y[o] = P[o] + beta*y[o-1]
    for (int d = 1; d < OB; d <<= 1) {
        float v = 0.f, g = 0.f, pv = 0.f, pg = 0.f;
        if (t < OB) {
            v = sv[t]; g = sg[t];
            if (t >= d) { pv = sv[t - d]; pg = sg[t - d]; }
        }
        __syncthreads();
        if (t < OB && t >= d) { sv[t] = v + g * pv; sg[t] = g * pg; }
        __syncthreads();
    }
    if (t < nact)
        out[(size_t)c * NOUT + blk * OB + t] = sv[t];
    if (t == nact - 1)
        carryOut[c * NBLK + blk] = sv[t];
}

// ---------------- IIR part 2: per-channel carries (incl. circular wrap) ----------------
__global__ void iir_part2(const float* __restrict__ comp, const float* __restrict__ alpha_leak,
                          const float* __restrict__ li_kernel,
                          const float* __restrict__ carryOut, float* __restrict__ D) {
    int c = threadIdx.x;
    if (c >= NCH) return;
    float alpha = alpha_leak[0];
    float k0 = li_kernel[0], k1 = li_kernel[1];
    const float* c0 = comp + (size_t)c * LN;
    const float* c1 = (c + 1 < NCH) ? comp + (size_t)(c + 1) * LN : nullptr;
    // decayed sum over the tail [LN-KTAIL, LN) ending at LN-1
    float tail = 0.f, ap = 1.f;
    for (int j = 0; j < KTAIL; j++) {
        int g = LN - 1 - j;
        float u0 = c0[g];
        float u1 = c1 ? c1[g] : 0.f;
        float v = k0 * u0 + k1 * u1; v = v > 0.f ? v : 0.f;
        tail += ap * v;
        ap *= alpha;          // ends at alpha^KTAIL
    }
    // block 51 spans 2000 samples; alpha^10240 == 0, so deeper terms vanish
    float D0 = tail + ap * carryOut[c * NBLK + (NBLK - 1)]
             + powf(alpha, (float)(KTAIL + 2000)) * carryOut[c * NBLK + (NBLK - 2)];
    D[c * NBLK + 0] = D0;                       // circular wrap carry into block 0
    for (int b = 1; b < NBLK; b++)
        D[c * NBLK + b] = carryOut[c * NBLK + b - 1];
}

// ---------------- IIR part 3: add decayed carry into each output ----------------
__global__ void iir_part3(const float* __restrict__ D, const float* __restrict__ alpha_leak,
                          float* __restrict__ out) {
    int idx = blockIdx.x * 256 + threadIdx.x;
    if (idx >= NCH * NOUT) return;
    int c = idx / NOUT, m = idx - c * NOUT;
    int b = m / OB, o = m - b * OB;
    float alpha = alpha_leak[0];
    float beta = powf(alpha, (float)DSR);
    float dec = powf(beta, (float)(o + 1));     // underflows to 0 quickly — fine
    out[idx] += dec * D[c * NBLK + b];
}

extern "C" void kernel_launch(void* const* d_in, const int* in_sizes, int n_in,
                              void* d_out, int out_size, void* d_ws, size_t ws_size,
                              hipStream_t stream) {
    const float* x  = (const float*)d_in[0];
    const float* Hr = (const float*)d_in[1];
    const float* Hi = (const float*)d_in[2];
    const float* ac = (const float*)d_in[3];
    const float* al = (const float*)d_in[4];
    const float* li = (const float*)d_in[5];
    float* out = (float*)d_out;

    char* ws = (char*)d_ws;
    size_t off = 0;
    auto alloc = [&](size_t bytes) -> void* {
        void* p = ws + off;
        off += (bytes + 255) & ~(size_t)255;
        return p;
    };
    float2* Xf     = (float2*)alloc((size_t)LN * sizeof(float2));
    float*  comp   = (float*) alloc((size_t)NCH * LN * sizeof(float));
    float*  cOut   = (float*) alloc((size_t)NCH * NBLK * sizeof(float));
    float*  Dbuf   = (float*) alloc((size_t)NCH * NBLK * sizeof(float));
    // FFT ping-pong buffers, chunked over channel pairs to fit ws
    size_t remain = (ws_size > off) ? (ws_size - off) : 0;
    int chunk = (int)(remain / (2 * (size_t)LN * sizeof(float2)));
    if (chunk > 13) chunk = 13;
    if (chunk < 1)  chunk = 1;
    float2* bufA = (float2*)alloc((size_t)chunk * LN * sizeof(float2));
    float2* bufB = (float2*)alloc((size_t)chunk * LN * sizeof(float2));

    dim3 tb(32, 8, 1);

    // ---- forward FFT of x: natural order, four-step with explicit transposes ----
    pack_x<<<LN / 256, 256, 0, stream>>>(x, bufA);
    transpose_c<<<dim3(N2/32, N1/32, 1), tb, 0, stream>>>(bufA, bufB, N1, N2);
    fft_rows<N1, -1, 1><<<N2, 256, 0, stream>>>(bufB, bufB, N2);
    transpose_c<<<dim3(N1/32, N2/32, 1), tb, 0, stream>>>(bufB, bufA, N2, N1);
    fft_rows<N2, -1, 0><<<N1, 256, 0, stream>>>(bufA, bufA, N1);
    transpose_c<<<dim3(N2/32, N1/32, 1), tb, 0, stream>>>(bufA, Xf, N1, N2);

    // ---- batched inverse FFTs (sign=+1, scaled in finish) of paired spectra ----
    for (int ci = 0; ci < NPAIR; ci += chunk) {
        int np = NPAIR - ci; if (np > chunk) np = chunk;
        build_w<<<(np * (LN/2)) / 256, 256, 0, stream>>>(Hr, Hi, Xf, bufA, ci, np);
        transpose_c<<<dim3(N2/32, N1/32, np), tb, 0, stream>>>(bufA, bufB, N1, N2);
        fft_rows<N1, 1, 1><<<N2 * np, 256, 0, stream>>>(bufB, bufB, N2);
        transpose_c<<<dim3(N1/32, N2/32, np), tb, 0, stream>>>(bufB, bufA, N2, N1);
        fft_rows<N2, 1, 0><<<N1 * np, 256, 0, stream>>>(bufA, bufA, N1);
        ifft_finish<<<dim3(N2/32, N1/32, np), tb, 0, stream>>>(bufA, comp, ac, ci);
    }

    // ---- leaky integration (time-domain, exact to fp precision) + downsample ----
    iir_part1<<<dim3(NBLK, NCH, 1), 256, 0, stream>>>(comp, al, li, out, cOut);
    iir_part2<<<1, 256, 0, stream>>>(comp, al, li, cOut, Dbuf);
    iir_part3<<<(NCH * NOUT + 255) / 256, 256, 0, stream>>>(Dbuf, al, out);
}

// Round 2
// 1165.746 us; speedup vs baseline: 1.0505x; 1.0505x over previous
//
#include <hip/hip_runtime.h>
#include <math.h>

#define LN    524288        // signal length, 2^19
#define N1    512           // first-FFT length
#define N2    1024          // second-FFT length
#define NCH   129
#define DSR   80            // downsample rate
#define NOUT  6553          // output frames per channel
#define OB2   64            // outputs per IIR block
#define NBLK  103           // ceil(NOUT/OB2)
#define SPB   (OB2*DSR)     // 5120 samples per IIR block
#define TPW   20            // samples per thread in IIR
#define NPAIR 65            // ceil(129/2) channel pairs
#define KTAIL 48            // LN - NOUT*DSR

__device__ __forceinline__ float2 cmulf(float2 a, float2 b) {
    return make_float2(a.x*b.x - a.y*b.y, a.x*b.y + a.y*b.x);
}

// ---------------- pack real x into complex buffer ----------------
__global__ void pack_x(const float* __restrict__ x, float2* __restrict__ dst) {
    int i = blockIdx.x * 256 + threadIdx.x;
    dst[i] = make_float2(x[i], 0.f);
}

// ---------------- tiled complex transpose (forward path only) ----------------
__global__ void transpose_c(const float2* __restrict__ src, float2* __restrict__ dst,
                            int R, int Cc) {
    __shared__ float2 tile[32][33];
    size_t boff = (size_t)blockIdx.z * LN;
    src += boff; dst += boff;
    int x  = blockIdx.x * 32 + threadIdx.x;
    int y0 = blockIdx.y * 32 + threadIdx.y;
#pragma unroll
    for (int i = 0; i < 32; i += 8)
        tile[threadIdx.y + i][threadIdx.x] = src[(size_t)(y0 + i) * Cc + x];
    __syncthreads();
    int xo  = blockIdx.y * 32 + threadIdx.x;
    int yo0 = blockIdx.x * 32 + threadIdx.y;
#pragma unroll
    for (int i = 0; i < 32; i += 8)
        dst[(size_t)(yo0 + i) * R + xo] = tile[threadIdx.x][threadIdx.y + i];
}

// ---------------- LDS Stockham radix-2 row FFT, natural in/out ----------------
template<int M, int SIGN, int TW>
__global__ __launch_bounds__(256) void fft_rows(const float2* __restrict__ src,
                                                float2* __restrict__ dst,
                                                int rows_per_batch) {
    __shared__ float2 ping[M];
    __shared__ float2 pong[M];
    size_t rowg = blockIdx.x;
    const float2* srow = src + rowg * M;
    float2* drow = dst + rowg * M;
    int row = (int)(rowg % (size_t)rows_per_batch);
    int t = threadIdx.x;
    for (int i = t; i < M; i += 256) ping[i] = srow[i];
    __syncthreads();
    float2* a = ping;
    float2* b = pong;
    for (int Ns = 1; Ns < M; Ns <<= 1) {
        for (int j = t; j < M/2; j += 256) {
            int jm = j & (Ns - 1);
            float2 v0 = a[j];
            float2 v1 = a[j + M/2];
            float ang = (float)SIGN * 3.14159265358979323846f * ((float)jm / (float)Ns);
            float s, c;
            __sincosf(ang, &s, &c);
            float2 w = make_float2(v1.x*c - v1.y*s, v1.x*s + v1.y*c);
            int d0 = ((j & ~(Ns - 1)) << 1) | jm;
            b[d0]      = make_float2(v0.x + w.x, v0.y + w.y);
            b[d0 + Ns] = make_float2(v0.x - w.x, v0.y - w.y);
        }
        __syncthreads();
        float2* tmp = a; a = b; b = tmp;
    }
    if (TW) {
        const float c2pi = 6.28318530717958647692f / (float)LN;
        for (int i = t; i < M; i += 256) {
            float2 v = a[i];
            unsigned prod = ((unsigned)row * (unsigned)i) & (unsigned)(LN - 1);
            float ang = (float)SIGN * c2pi * (float)prod;
            float s, c;
            __sincosf(ang, &s, &c);
            drow[i] = make_float2(v.x*c - v.y*s, v.x*s + v.y*c);
        }
    } else {
        for (int i = t; i < M; i += 256) drow[i] = a[i];
    }
}

// ---------------- batched column FFT (replaces transpose + fft_rows<512> + transpose) ----
// src: W [512 r][1024 c] per pair. For 8 columns per workgroup: 512-FFT over r,
// post-twiddle e^{+2pi i c j/LN}, write D[j][c] directly (layout fft_rows<1024> reads).
__global__ __launch_bounds__(256) void fftA(const float2* __restrict__ src,
                                            float2* __restrict__ dst) {
    __shared__ float bufRe[2][512][9];
    __shared__ float bufIm[2][512][9];
    int pl = blockIdx.x >> 7;            // pair-local index
    int c_base = (blockIdx.x & 127) * 8;
    const float2* W = src + (size_t)pl * LN;
    float2* Dp = dst + (size_t)pl * LN;
    int t = threadIdx.x;
    int lc = t & 7;       // column within tile
    int lr = t >> 3;      // 0..31
    for (int rb = 0; rb < 512; rb += 32) {
        int r = rb + lr;
        float2 v = W[(size_t)r * N2 + c_base + lc];
        bufRe[0][r][lc] = v.x;
        bufIm[0][r][lc] = v.y;
    }
    __syncthreads();
    int p = 0;
    for (int Ns = 1; Ns < 512; Ns <<= 1) {
#pragma unroll
        for (int jb = 0; jb < 256; jb += 32) {
            int j = jb + lr;
            int jm = j & (Ns - 1);
            float are = bufRe[p][j][lc],       aim = bufIm[p][j][lc];
            float bre = bufRe[p][j + 256][lc], bim = bufIm[p][j + 256][lc];
            float ang = 3.14159265358979323846f * ((float)jm / (float)Ns); // SIGN=+1
            float s, c;
            __sincosf(ang, &s, &c);
            float wre = bre*c - bim*s, wim = bre*s + bim*c;
            int d0 = ((j & ~(Ns - 1)) << 1) | jm;
            bufRe[p^1][d0][lc]      = are + wre;  bufIm[p^1][d0][lc]      = aim + wim;
            bufRe[p^1][d0 + Ns][lc] = are - wre;  bufIm[p^1][d0 + Ns][lc] = aim - wim;
        }
        __syncthreads();
        p ^= 1;
    }
    const float c2pi = 6.28318530717958647692f / (float)LN;
    unsigned cg = (unsigned)(c_base + lc);
#pragma unroll
    for (int jb = 0; jb < 512; jb += 32) {
        int j = jb + lr;
        float re = bufRe[p][j][lc], im = bufIm[p][j][lc];
        unsigned prod = (cg * (unsigned)j) & (unsigned)(LN - 1);
        float ang = c2pi * (float)prod;
        float s, c;
        __sincosf(ang, &s, &c);
        Dp[(size_t)j * N2 + c_base + lc] = make_float2(re*c - im*s, re*s + im*c);
    }
}

// ---------------- build paired Hermitian spectra W = Herm(Ya) + i*Herm(Yb) ----------------
__global__ void build_w(const float* __restrict__ Hr, const float* __restrict__ Hi,
                        const float2* __restrict__ X, float2* __restrict__ W,
                        int pair0, int npairs) {
    size_t tid = (size_t)blockIdx.x * 256 + threadIdx.x;
    const size_t half = LN / 2;
    int pl = (int)(tid / half);
    if (pl >= npairs) return;
    unsigned k = (unsigned)(tid % half);
    int p = pair0 + pl;
    int ca = 2*p, cb = 2*p + 1;
    const float* Har = Hr + (size_t)ca * LN;
    const float* Hai = Hi + (size_t)ca * LN;
    const bool hasB = (cb < NCH);
    const float* Hbr = hasB ? (Hr + (size_t)cb * LN) : nullptr;
    const float* Hbi = hasB ? (Hi + (size_t)cb * LN) : nullptr;
    float2* Wp = W + (size_t)pl * LN;
    if (k == 0) {
        for (int kk = 0; kk < 2; kk++) {
            unsigned idx = kk ? (unsigned)half : 0u;
            float2 Xv = X[idx];
            float2 Ya = cmulf(make_float2(Har[idx], Hai[idx]), Xv);
            float br = 0.f;
            if (hasB) { float2 Yb = cmulf(make_float2(Hbr[idx], Hbi[idx]), Xv); br = Yb.x; }
            Wp[idx] = make_float2(Ya.x, br);
        }
        return;
    }
    unsigned kL = (unsigned)LN - k;
    float2 X1 = X[k], X2 = X[kL];
    float2 a1 = cmulf(make_float2(Har[k],  Hai[k]),  X1);
    float2 a2 = cmulf(make_float2(Har[kL], Hai[kL]), X2);
    float2 b1 = make_float2(0.f, 0.f), b2 = make_float2(0.f, 0.f);
    if (hasB) {
        b1 = cmulf(make_float2(Hbr[k],  Hbi[k]),  X1);
        b2 = cmulf(make_float2(Hbr[kL], Hbi[kL]), X2);
    }
    float yar = 0.5f*(a1.x + a2.x), yai = 0.5f*(a1.y - a2.y);
    float ybr = 0.5f*(b1.x + b2.x), ybi = 0.5f*(b1.y - b2.y);
    Wp[k]  = make_float2(yar - ybi, yai + ybr);
    float yar2 = 0.5f*(a2.x + a1.x), yai2 = 0.5f*(a2.y - a1.y);
    float ybr2 = 0.5f*(b2.x + b1.x), ybi2 = 0.5f*(b2.y - b1.y);
    Wp[kL] = make_float2(yar2 - ybi2, yai2 + ybr2);
}

// ---------------- final transpose of IFFT + 1/L scale + power-law ----------------
__global__ void ifft_finish(const float2* __restrict__ src, float* __restrict__ comp,
                            const float* __restrict__ alpha_comp, int pair0) {
    __shared__ float2 tile[32][33];
    int pl = blockIdx.z;
    int p = pair0 + pl;
    int ca = 2*p, cb = 2*p + 1;
    const float2* s = src + (size_t)pl * LN;
    int x  = blockIdx.x * 32 + threadIdx.x;   // col (m) in [0,1024)
    int y0 = blockIdx.y * 32 + threadIdx.y;   // row (j) in [0,512)
#pragma unroll
    for (int i = 0; i < 32; i += 8)
        tile[threadIdx.y + i][threadIdx.x] = s[(size_t)(y0 + i) * N2 + x];
    __syncthreads();
    float aa = alpha_comp[ca];
    float ab = (cb < NCH) ? alpha_comp[cb] : 1.f;
    const float invL = 1.f / (float)LN;
    int xo  = blockIdx.y * 32 + threadIdx.x;  // j
    int yo0 = blockIdx.x * 32 + threadIdx.y;  // m
#pragma unroll
    for (int i = 0; i < 32; i += 8) {
        int yo = yo0 + i;
        float2 v = tile[threadIdx.x][threadIdx.y + i];
        size_t n = (size_t)yo * N1 + xo;      // n = 512*m + j
        float ra = v.x * invL;
        float rb = v.y * invL;
        comp[(size_t)ca * LN + n] = copysignf(powf(fabsf(ra), aa), ra);
        if (cb < NCH)
            comp[(size_t)cb * LN + n] = copysignf(powf(fabsf(rb), ab), rb);
    }
}

// ---------------- leaky IIR part 1: thread-per-20-samples + affine shuffle scan ----------
// grid: (NBLK, NCH), block 256. Block = 64 outputs = 5120 samples.
__global__ __launch_bounds__(256) void iir_part1(
    const float* __restrict__ comp, const float* __restrict__ alpha_leak,
    const float* __restrict__ li_kernel, float* __restrict__ out,
    float* __restrict__ carryOut) {
    __shared__ float win[SPB + SPB/TPW];   // 5376 floats, pad every 20 (stride 21)
    __shared__ float wv[4], wg[4];
    int blk = blockIdx.x;
    int c = blockIdx.y;
    int t = threadIdx.x;
    float alpha = alpha_leak[0];
    float k0 = li_kernel[0], k1 = li_kernel[1];
    int base = blk * SPB;
    const int cap = NOUT * DSR;   // 524240
    const float* c0 = comp + (size_t)c * LN;
    const float* c1 = (c + 1 < NCH) ? comp + (size_t)(c + 1) * LN : nullptr;
    for (int i = t; i < SPB; i += 256) {
        int g = base + i;
        float v = 0.f;
        if (g < cap) {
            float u0 = c0[g];
            float u1 = c1 ? c1[g] : 0.f;
            v = fmaxf(k0 * u0 + k1 * u1, 0.f);
        }
        win[i + i / TPW] = v;
    }
    __syncthreads();
    // per-thread IIR over its 20 samples (zero carry-in): v = sum alpha^{19-i} s[i]
    float v = 0.f;
    int lbase = 21 * t;
#pragma unroll
    for (int i = 0; i < TPW; i++)
        v = fmaf(alpha, v, win[lbase + i]);
    float g = powf(alpha, (float)TPW);    // per-thread gain alpha^20
    // intra-wave inclusive affine scan (lane order = time order)
    int lid = t & 63, wid = t >> 6;
#pragma unroll
    for (int d = 1; d < 64; d <<= 1) {
        float pv = __shfl_up(v, d);
        float pg = __shfl_up(g, d);
        if (lid >= d) { v = fmaf(g, pv, v); g = g * pg; }
    }
    if (lid == 63) { wv[wid] = v; wg[wid] = g; }
    __syncthreads();
    // prefix affine from preceding waves
    float cv = 0.f;
#pragma unroll
    for (int w = 0; w < 3; w++)
        if (w < wid) cv = wv[w] + wg[w] * cv;
    float vf = fmaf(g, cv, v);            // inclusive value = y at sample 20t+19 (rel.)
    int nact = NOUT - blk * OB2; if (nact > OB2) nact = OB2;
    if ((t & 3) == 3) {
        int o = t >> 2;
        if (o < nact)
            out[(size_t)c * NOUT + blk * OB2 + o] = vf;
    }
    if (t == 4 * nact - 1)
        carryOut[c * NBLK + blk] = vf;
}

// ---------------- IIR part 2: per-channel carries (incl. circular wrap) ----------------
__global__ void iir_part2(const float* __restrict__ comp, const float* __restrict__ alpha_leak,
                          const float* __restrict__ li_kernel,
                          const float* __restrict__ carryOut, float* __restrict__ D) {
    int c = threadIdx.x;
    if (c >= NCH) return;
    float alpha = alpha_leak[0];
    float k0 = li_kernel[0], k1 = li_kernel[1];
    const float* c0 = comp + (size_t)c * LN;
    const float* c1 = (c + 1 < NCH) ? comp + (size_t)(c + 1) * LN : nullptr;
    float tail = 0.f, ap = 1.f;
    for (int j = 0; j < KTAIL; j++) {
        int g = LN - 1 - j;
        float u0 = c0[g];
        float u1 = c1 ? c1[g] : 0.f;
        float v = k0 * u0 + k1 * u1; v = v > 0.f ? v : 0.f;
        tail += ap * v;
        ap *= alpha;          // ends at alpha^KTAIL
    }
    // last block spans 2000 samples; alpha^(2000+5120) ~ 0, so two carry terms suffice
    float D0 = tail + ap * carryOut[c * NBLK + (NBLK - 1)]
             + powf(alpha, (float)(KTAIL + 2000)) * carryOut[c * NBLK + (NBLK - 2)];
    D[c * NBLK + 0] = D0;                       // circular wrap carry into block 0
    for (int b = 1; b < NBLK; b++)
        D[c * NBLK + b] = carryOut[c * NBLK + b - 1];
}

// ---------------- IIR part 3: add decayed carry into each output ----------------
__global__ void iir_part3(const float* __restrict__ D, const float* __restrict__ alpha_leak,
                          float* __restrict__ out) {
    int idx = blockIdx.x * 256 + threadIdx.x;
    if (idx >= NCH * NOUT) return;
    int c = idx / NOUT, m = idx - c * NOUT;
    int b = m / OB2, o = m - b * OB2;
    float alpha = alpha_leak[0];
    float beta = powf(alpha, (float)DSR);
    float dec = powf(beta, (float)(o + 1));
    out[idx] += dec * D[c * NBLK + b];
}

extern "C" void kernel_launch(void* const* d_in, const int* in_sizes, int n_in,
                              void* d_out, int out_size, void* d_ws, size_t ws_size,
                              hipStream_t stream) {
    const float* x  = (const float*)d_in[0];
    const float* Hr = (const float*)d_in[1];
    const float* Hi = (const float*)d_in[2];
    const float* ac = (const float*)d_in[3];
    const float* al = (const float*)d_in[4];
    const float* li = (const float*)d_in[5];
    float* out = (float*)d_out;

    char* ws = (char*)d_ws;
    size_t off = 0;
    auto alloc = [&](size_t bytes) -> void* {
        void* p = ws + off;
        off += (bytes + 255) & ~(size_t)255;
        return p;
    };
    float2* Xf     = (float2*)alloc((size_t)LN * sizeof(float2));
    float*  comp   = (float*) alloc((size_t)NCH * LN * sizeof(float));
    float*  cOut   = (float*) alloc((size_t)NCH * NBLK * sizeof(float));
    float*  Dbuf   = (float*) alloc((size_t)NCH * NBLK * sizeof(float));
    size_t remain = (ws_size > off) ? (ws_size - off) : 0;
    int chunk = (int)(remain / (2 * (size_t)LN * sizeof(float2)));
    if (chunk > 13) chunk = 13;
    if (chunk < 1)  chunk = 1;
    float2* bufA = (float2*)alloc((size_t)chunk * LN * sizeof(float2));
    float2* bufB = (float2*)alloc((size_t)chunk * LN * sizeof(float2));

    dim3 tb(32, 8, 1);

    // ---- forward FFT of x (four-step with transposes; small, one signal) ----
    pack_x<<<LN / 256, 256, 0, stream>>>(x, bufA);
    transpose_c<<<dim3(N2/32, N1/32, 1), tb, 0, stream>>>(bufA, bufB, N1, N2);
    fft_rows<N1, -1, 1><<<N2, 256, 0, stream>>>(bufB, bufB, N2);
    transpose_c<<<dim3(N1/32, N2/32, 1), tb, 0, stream>>>(bufB, bufA, N2, N1);
    fft_rows<N2, -1, 0><<<N1, 256, 0, stream>>>(bufA, bufA, N1);
    transpose_c<<<dim3(N2/32, N1/32, 1), tb, 0, stream>>>(bufA, Xf, N1, N2);

    // ---- batched inverse FFTs of paired spectra: build -> fftA -> fft1024 -> finish ----
    for (int ci = 0; ci < NPAIR; ci += chunk) {
        int np = NPAIR - ci; if (np > chunk) np = chunk;
        build_w<<<(np * (LN/2)) / 256, 256, 0, stream>>>(Hr, Hi, Xf, bufA, ci, np);
        fftA<<<np * 128, 256, 0, stream>>>(bufA, bufB);
        fft_rows<N2, 1, 0><<<N1 * np, 256, 0, stream>>>(bufB, bufB, N1);
        ifft_finish<<<dim3(N2/32, N1/32, np), tb, 0, stream>>>(bufB, comp, ac, ci);
    }

    // ---- leaky integration (time-domain, exact to fp precision) + downsample ----
    iir_part1<<<dim3(NBLK, NCH, 1), 256, 0, stream>>>(comp, al, li, out, cOut);
    iir_part2<<<1, 256, 0, stream>>>(comp, al, li, cOut, Dbuf);
    iir_part3<<<(NCH * NOUT + 255) / 256, 256, 0, stream>>>(Dbuf, al, out);
}

// Round 3
// 1027.685 us; speedup vs baseline: 1.1916x; 1.1343x over previous
//
#include <hip/hip_runtime.h>
#include <math.h>

#define LN    524288        // signal length, 2^19
#define N1    512           // first-FFT length (column FFT)
#define N2    1024          // second-FFT length (row FFT)
#define NCH   129
#define DSR   80            // downsample rate
#define NOUT  6553          // output frames per channel
#define OB2   64            // outputs per IIR block
#define NBLK  103           // ceil(NOUT/OB2)
#define SPB   (OB2*DSR)     // 5120 samples per IIR block
#define TPW   20            // samples per thread in IIR
#define NPAIR 65            // ceil(129/2) channel pairs
#define KTAIL 48            // LN - NOUT*DSR

__device__ __forceinline__ float2 cmulf(float2 a, float2 b) {
    return make_float2(a.x*b.x - a.y*b.y, a.x*b.y + a.y*b.x);
}

// ---------------- pack real x into complex buffer ----------------
__global__ void pack_x(const float* __restrict__ x, float2* __restrict__ dst) {
    int i = blockIdx.x * 256 + threadIdx.x;
    dst[i] = make_float2(x[i], 0.f);
}

// ---------------- tiled complex transpose (forward path only) ----------------
__global__ void transpose_c(const float2* __restrict__ src, float2* __restrict__ dst,
                            int R, int Cc) {
    __shared__ float2 tile[32][33];
    size_t boff = (size_t)blockIdx.z * LN;
    src += boff; dst += boff;
    int x  = blockIdx.x * 32 + threadIdx.x;
    int y0 = blockIdx.y * 32 + threadIdx.y;
#pragma unroll
    for (int i = 0; i < 32; i += 8)
        tile[threadIdx.y + i][threadIdx.x] = src[(size_t)(y0 + i) * Cc + x];
    __syncthreads();
    int xo  = blockIdx.y * 32 + threadIdx.x;
    int yo0 = blockIdx.x * 32 + threadIdx.y;
#pragma unroll
    for (int i = 0; i < 32; i += 8)
        dst[(size_t)(yo0 + i) * R + xo] = tile[threadIdx.x][threadIdx.y + i];
}

// ---------------- LDS Stockham radix-2 row FFT, natural in/out ----------------
template<int M, int SIGN, int TW>
__global__ __launch_bounds__(256) void fft_rows(const float2* __restrict__ src,
                                                float2* __restrict__ dst,
                                                int rows_per_batch) {
    __shared__ float2 ping[M];
    __shared__ float2 pong[M];
    size_t rowg = blockIdx.x;
    const float2* srow = src + rowg * M;
    float2* drow = dst + rowg * M;
    int row = (int)(rowg % (size_t)rows_per_batch);
    int t = threadIdx.x;
    for (int i = t; i < M; i += 256) ping[i] = srow[i];
    __syncthreads();
    float2* a = ping;
    float2* b = pong;
    for (int Ns = 1; Ns < M; Ns <<= 1) {
        for (int j = t; j < M/2; j += 256) {
            int jm = j & (Ns - 1);
            float2 v0 = a[j];
            float2 v1 = a[j + M/2];
            float ang = (float)SIGN * 3.14159265358979323846f * ((float)jm / (float)Ns);
            float s, c;
            __sincosf(ang, &s, &c);
            float2 w = make_float2(v1.x*c - v1.y*s, v1.x*s + v1.y*c);
            int d0 = ((j & ~(Ns - 1)) << 1) | jm;
            b[d0]      = make_float2(v0.x + w.x, v0.y + w.y);
            b[d0 + Ns] = make_float2(v0.x - w.x, v0.y - w.y);
        }
        __syncthreads();
        float2* tmp = a; a = b; b = tmp;
    }
    if (TW) {
        const float c2pi = 6.28318530717958647692f / (float)LN;
        for (int i = t; i < M; i += 256) {
            float2 v = a[i];
            unsigned prod = ((unsigned)row * (unsigned)i) & (unsigned)(LN - 1);
            float ang = (float)SIGN * c2pi * (float)prod;
            float s, c;
            __sincosf(ang, &s, &c);
            drow[i] = make_float2(v.x*c - v.y*s, v.x*s + v.y*c);
        }
    } else {
        for (int i = t; i < M; i += 256) drow[i] = a[i];
    }
}

// ---------------- Hermitian-combine W[k],W[L-k] from H,X (X real => X[L-k]=conj X[k]) ----
__device__ __forceinline__ void herm2(float2 X1,
                                      float har,  float hai,  float hbr,  float hbi,
                                      float har2, float hai2, float hbr2, float hbi2,
                                      bool hasB, float2& Wk, float2& WkL) {
    // a1 = Ha(k)*X1 ; a2 = Ha(kL)*conj(X1)
    float2 a1 = make_float2(har*X1.x - hai*X1.y, har*X1.y + hai*X1.x);
    float2 a2 = make_float2(har2*X1.x + hai2*X1.y, hai2*X1.x - har2*X1.y);
    float yar = 0.5f*(a1.x + a2.x), yai = 0.5f*(a1.y - a2.y);
    float ybr = 0.f, ybi = 0.f;
    if (hasB) {
        float2 b1 = make_float2(hbr*X1.x - hbi*X1.y, hbr*X1.y + hbi*X1.x);
        float2 b2 = make_float2(hbr2*X1.x + hbi2*X1.y, hbi2*X1.x - hbr2*X1.y);
        ybr = 0.5f*(b1.x + b2.x); ybi = 0.5f*(b1.y - b2.y);
    }
    Wk  = make_float2(yar - ybi, yai + ybr);
    WkL = make_float2(yar + ybi, ybr - yai);   // derived: yar2=yar, yai2=-yai, etc.
}

// ---------------- fused build_w + 512-point column FFT (in-place DIF, sign +1) --------
// Block b (0..31) owns A-cols {16b..16b+15} and mirror cols {1024-16b-15..1024-16b}
// (block 0: slot16 repurposed for self-mirrored col 512; col 0 self-mirrored in-rows).
// Output rows written at true j = bitrev9(p), with four-step twiddle e^{+2pi i c j/L}.
__global__ __launch_bounds__(512) void kA(const float* __restrict__ Hr,
                                          const float* __restrict__ Hi,
                                          const float2* __restrict__ X,
                                          float2* __restrict__ D1, int pair0) {
    __shared__ float sRe[512][33];
    __shared__ float sIm[512][33];
    int bb = blockIdx.x;            // column group
    int pl = blockIdx.y;            // pair within chunk
    int p  = pair0 + pl;
    int ca = 2*p, cb = 2*p + 1;
    bool hasB = (cb < NCH);
    const float* Har = Hr + (size_t)ca * LN;
    const float* Hai = Hi + (size_t)ca * LN;
    const float* Hbr = hasB ? (Hr + (size_t)cb * LN) : Har;
    const float* Hbi = hasB ? (Hi + (size_t)cb * LN) : Hai;
    float2* Dp = D1 + (size_t)pl * LN;
    unsigned c_base = 16u * bb;
    int t = threadIdx.x;

    // ---- phase 1: Hermitian build of 32 columns directly into LDS ----
    for (int e = t; e < 16*512; e += 512) {
        unsigned c_off = (unsigned)(e & 15);
        unsigned r     = (unsigned)(e >> 4);
        if (bb == 0 && c_off == 0) {
            // col 0 (self-mirrored rows; bins 0 and L/2 special)
            if (r == 0 || r == 256) {
                unsigned k = 1024u * r;     // 0 or L/2
                float2 Xv = X[k];
                float2 a1 = cmulf(make_float2(Har[k], Hai[k]), Xv);
                float br = 0.f;
                if (hasB) { float2 b1 = cmulf(make_float2(Hbr[k], Hbi[k]), Xv); br = b1.x; }
                sRe[r][0] = a1.x; sIm[r][0] = br;
            } else if (r < 256) {
                unsigned k = 1024u * r, kL = 1024u * (512 - r);
                float2 Wk, WkL;
                herm2(X[k], Har[k], Hai[k], Hbr[k], Hbi[k],
                      Har[kL], Hai[kL], Hbr[kL], Hbi[kL], hasB, Wk, WkL);
                sRe[r][0] = Wk.x;        sIm[r][0] = Wk.y;
                sRe[512 - r][0] = WkL.x; sIm[512 - r][0] = WkL.y;
            }
            // col 512 -> slot 16 (self-mirrored: rows r <-> 511-r)
            if (r < 256) {
                unsigned k = 1024u * r + 512u, kL = 1024u * (511 - r) + 512u;
                float2 Wk, WkL;
                herm2(X[k], Har[k], Hai[k], Hbr[k], Hbi[k],
                      Har[kL], Hai[kL], Hbr[kL], Hbi[kL], hasB, Wk, WkL);
                sRe[r][16] = Wk.x;         sIm[r][16] = Wk.y;
                sRe[511 - r][16] = WkL.x;  sIm[511 - r][16] = WkL.y;
            }
        } else {
            unsigned c = c_base + c_off;
            unsigned k  = 1024u * r + c;
            unsigned kL = 1024u * (511 - r) + (1024u - c);
            float2 Wk, WkL;
            herm2(X[k], Har[k], Hai[k], Hbr[k], Hbi[k],
                  Har[kL], Hai[kL], Hbr[kL], Hbi[kL], hasB, Wk, WkL);
            sRe[r][c_off] = Wk.x;               sIm[r][c_off] = Wk.y;
            sRe[511 - r][16 + c_off] = WkL.x;   sIm[511 - r][16 + c_off] = WkL.y;
        }
    }
    __syncthreads();

    // ---- phase 2: in-place radix-2 DIF 512-FFT (sign +1) over rows, 32 columns ----
    int j   = t & 255;
    int ch0 = (t >> 8) << 4;     // 0 or 16
    for (int h = 256; h >= 1; h >>= 1) {
        int q = j & (h - 1);
        int base = ((j & ~(h - 1)) << 1) | q;
        float ang = 3.14159265358979323846f * (float)q / (float)h;  // +pi*q/h
        float s, c;
        __sincosf(ang, &s, &c);
#pragma unroll
        for (int cc = ch0; cc < ch0 + 16; ++cc) {
            float are = sRe[base][cc],     aim = sIm[base][cc];
            float bre = sRe[base + h][cc], bim = sIm[base + h][cc];
            sRe[base][cc] = are + bre;  sIm[base][cc] = aim + bim;
            float dre = are - bre, dim = aim - bim;
            sRe[base + h][cc] = dre*c - dim*s;
            sIm[base + h][cc] = dre*s + dim*c;
        }
        __syncthreads();
    }

    // ---- phase 3: bitrev row, four-step twiddle, write D1[j][truec] ----
    const float c2pi = 6.28318530717958647692f / (float)LN;
    for (int e = t; e < 512*32; e += 512) {
        int slot = e & 31;
        int pos  = e >> 5;
        unsigned jj = __brev((unsigned)pos) >> 23;   // bitrev9
        unsigned truec = (slot < 16) ? (c_base + (unsigned)slot)
                       : ((bb == 0 && slot == 16) ? 512u
                                                  : (1024u - c_base - (unsigned)(slot - 16)));
        float re = sRe[pos][slot], im = sIm[pos][slot];
        unsigned prod = (jj * truec) & (unsigned)(LN - 1);
        float ang = c2pi * (float)prod;
        float s, c;
        __sincosf(ang, &s, &c);
        Dp[(size_t)jj * N2 + truec] = make_float2(re*c - im*s, re*s + im*c);
    }
}

// ---------------- final transpose of IFFT + 1/L scale + power-law ----------------
__global__ void ifft_finish(const float2* __restrict__ src, float* __restrict__ comp,
                            const float* __restrict__ alpha_comp, int pair0) {
    __shared__ float2 tile[32][33];
    int pl = blockIdx.z;
    int p = pair0 + pl;
    int ca = 2*p, cb = 2*p + 1;
    const float2* s = src + (size_t)pl * LN;
    int x  = blockIdx.x * 32 + threadIdx.x;   // col (m) in [0,1024)
    int y0 = blockIdx.y * 32 + threadIdx.y;   // row (j) in [0,512)
#pragma unroll
    for (int i = 0; i < 32; i += 8)
        tile[threadIdx.y + i][threadIdx.x] = s[(size_t)(y0 + i) * N2 + x];
    __syncthreads();
    float aa = alpha_comp[ca];
    float ab = (cb < NCH) ? alpha_comp[cb] : 1.f;
    const float invL = 1.f / (float)LN;
    int xo  = blockIdx.y * 32 + threadIdx.x;  // j
    int yo0 = blockIdx.x * 32 + threadIdx.y;  // m
#pragma unroll
    for (int i = 0; i < 32; i += 8) {
        int yo = yo0 + i;
        float2 v = tile[threadIdx.x][threadIdx.y + i];
        size_t n = (size_t)yo * N1 + xo;      // n = 512*m + j
        float ra = v.x * invL;
        float rb = v.y * invL;
        comp[(size_t)ca * LN + n] = copysignf(powf(fabsf(ra), aa), ra);
        if (cb < NCH)
            comp[(size_t)cb * LN + n] = copysignf(powf(fabsf(rb), ab), rb);
    }
}

// ---------------- leaky IIR part 1: thread-per-20-samples + affine shuffle scan ----------
__global__ __launch_bounds__(256) void iir_part1(
    const float* __restrict__ comp, const float* __restrict__ alpha_leak,
    const float* __restrict__ li_kernel, float* __restrict__ out,
    float* __restrict__ carryOut) {
    __shared__ float win[SPB + SPB/TPW];   // pad every 20 (stride 21)
    __shared__ float wv[4], wg[4];
    int blk = blockIdx.x;
    int c = blockIdx.y;
    int t = threadIdx.x;
    float alpha = alpha_leak[0];
    float k0 = li_kernel[0], k1 = li_kernel[1];
    int base = blk * SPB;
    const int cap = NOUT * DSR;   // 524240
    const float* c0 = comp + (size_t)c * LN;
    const float* c1 = (c + 1 < NCH) ? comp + (size_t)(c + 1) * LN : nullptr;
    for (int i = t; i < SPB; i += 256) {
        int g = base + i;
        float v = 0.f;
        if (g < cap) {
            float u0 = c0[g];
            float u1 = c1 ? c1[g] : 0.f;
            v = fmaxf(k0 * u0 + k1 * u1, 0.f);
        }
        win[i + i / TPW] = v;
    }
    __syncthreads();
    float v = 0.f;
    int lbase = 21 * t;
#pragma unroll
    for (int i = 0; i < TPW; i++)
        v = fmaf(alpha, v, win[lbase + i]);
    float g = powf(alpha, (float)TPW);
    int lid = t & 63, wid = t >> 6;
#pragma unroll
    for (int d = 1; d < 64; d <<= 1) {
        float pv = __shfl_up(v, d);
        float pg = __shfl_up(g, d);
        if (lid >= d) { v = fmaf(g, pv, v); g = g * pg; }
    }
    if (lid == 63) { wv[wid] = v; wg[wid] = g; }
    __syncthreads();
    float cv = 0.f;
#pragma unroll
    for (int w = 0; w < 3; w++)
        if (w < wid) cv = wv[w] + wg[w] * cv;
    float vf = fmaf(g, cv, v);
    int nact = NOUT - blk * OB2; if (nact > OB2) nact = OB2;
    if ((t & 3) == 3) {
        int o = t >> 2;
        if (o < nact)
            out[(size_t)c * NOUT + blk * OB2 + o] = vf;
    }
    if (t == 4 * nact - 1)
        carryOut[c * NBLK + blk] = vf;
}

// ---------------- IIR part 2: per-channel carries (incl. circular wrap) ----------------
__global__ void iir_part2(const float* __restrict__ comp, const float* __restrict__ alpha_leak,
                          const float* __restrict__ li_kernel,
                          const float* __restrict__ carryOut, float* __restrict__ D) {
    int c = threadIdx.x;
    if (c >= NCH) return;
    float alpha = alpha_leak[0];
    float k0 = li_kernel[0], k1 = li_kernel[1];
    const float* c0 = comp + (size_t)c * LN;
    const float* c1 = (c + 1 < NCH) ? comp + (size_t)(c + 1) * LN : nullptr;
    float tail = 0.f, ap = 1.f;
    for (int j = 0; j < KTAIL; j++) {
        int g = LN - 1 - j;
        float u0 = c0[g];
        float u1 = c1 ? c1[g] : 0.f;
        float v = k0 * u0 + k1 * u1; v = v > 0.f ? v : 0.f;
        tail += ap * v;
        ap *= alpha;
    }
    float D0 = tail + ap * carryOut[c * NBLK + (NBLK - 1)]
             + powf(alpha, (float)(KTAIL + 2000)) * carryOut[c * NBLK + (NBLK - 2)];
    D[c * NBLK + 0] = D0;
    for (int b = 1; b < NBLK; b++)
        D[c * NBLK + b] = carryOut[c * NBLK + b - 1];
}

// ---------------- IIR part 3: add decayed carry into each output ----------------
__global__ void iir_part3(const float* __restrict__ D, const float* __restrict__ alpha_leak,
                          float* __restrict__ out) {
    int idx = blockIdx.x * 256 + threadIdx.x;
    if (idx >= NCH * NOUT) return;
    int c = idx / NOUT, m = idx - c * NOUT;
    int b = m / OB2, o = m - b * OB2;
    float alpha = alpha_leak[0];
    float beta = powf(alpha, (float)DSR);
    float dec = powf(beta, (float)(o + 1));
    out[idx] += dec * D[c * NBLK + b];
}

extern "C" void kernel_launch(void* const* d_in, const int* in_sizes, int n_in,
                              void* d_out, int out_size, void* d_ws, size_t ws_size,
                              hipStream_t stream) {
    const float* x  = (const float*)d_in[0];
    const float* Hr = (const float*)d_in[1];
    const float* Hi = (const float*)d_in[2];
    const float* ac = (const float*)d_in[3];
    const float* al = (const float*)d_in[4];
    const float* li = (const float*)d_in[5];
    float* out = (float*)d_out;

    char* ws = (char*)d_ws;
    size_t off = 0;
    auto alloc = [&](size_t bytes) -> void* {
        void* p = ws + off;
        off += (bytes + 255) & ~(size_t)255;
        return p;
    };
    float2* Xf     = (float2*)alloc((size_t)LN * sizeof(float2));
    float*  comp   = (float*) alloc((size_t)NCH * LN * sizeof(float));
    float*  cOut   = (float*) alloc((size_t)NCH * NBLK * sizeof(float));
    float*  Dbuf   = (float*) alloc((size_t)NCH * NBLK * sizeof(float));
    size_t remain = (ws_size > off) ? (ws_size - off) : 0;
    int chunk = (int)(remain / ((size_t)LN * sizeof(float2)));
    if (chunk > NPAIR) chunk = NPAIR;
    if (chunk < 2)     chunk = 2;
    float2* bufB = (float2*)alloc((size_t)chunk * LN * sizeof(float2));

    dim3 tb(32, 8, 1);

    // ---- forward FFT of x (four-step with transposes; small, one signal) ----
    // use bufB[0..2LN) as ping-pong scratch (chunk >= 2)
    float2* fA = bufB;
    float2* fB = bufB + LN;
    pack_x<<<LN / 256, 256, 0, stream>>>(x, fA);
    transpose_c<<<dim3(N2/32, N1/32, 1), tb, 0, stream>>>(fA, fB, N1, N2);
    fft_rows<N1, -1, 1><<<N2, 256, 0, stream>>>(fB, fB, N2);
    transpose_c<<<dim3(N1/32, N2/32, 1), tb, 0, stream>>>(fB, fA, N2, N1);
    fft_rows<N2, -1, 0><<<N1, 256, 0, stream>>>(fA, fA, N1);
    transpose_c<<<dim3(N2/32, N1/32, 1), tb, 0, stream>>>(fA, Xf, N1, N2);

    // ---- batched inverse FFTs: fused herm-build+colFFT -> rowFFT -> finish ----
    for (int ci = 0; ci < NPAIR; ci += chunk) {
        int np = NPAIR - ci; if (np > chunk) np = chunk;
        kA<<<dim3(32, np), 512, 0, stream>>>(Hr, Hi, Xf, bufB, ci);
        fft_rows<N2, 1, 0><<<N1 * np, 256, 0, stream>>>(bufB, bufB, N1);
        ifft_finish<<<dim3(N2/32, N1/32, np), tb, 0, stream>>>(bufB, comp, ac, ci);
    }

    // ---- leaky integration (time-domain, exact to fp precision) + downsample ----
    iir_part1<<<dim3(NBLK, NCH, 1), 256, 0, stream>>>(comp, al, li, out, cOut);
    iir_part2<<<1, 256, 0, stream>>>(comp, al, li, cOut, Dbuf);
    iir_part3<<<(NCH * NOUT + 255) / 256, 256, 0, stream>>>(Dbuf, al, out);
}

// Round 4
// 953.395 us; speedup vs baseline: 1.2845x; 1.0779x over previous
//
#include <hip/hip_runtime.h>
#include <math.h>

#define LN    524288        // signal length, 2^19
#define N1    512           // first-FFT length (column FFT)
#define N2    1024          // second-FFT length (row FFT)
#define NCH   129
#define DSR   80            // downsample rate
#define NOUT  6553          // output frames per channel
#define OB2   64            // outputs per IIR block
#define NBLK  103           // ceil(NOUT/OB2)
#define SPB   (OB2*DSR)     // 5120 samples per IIR block
#define TPW   20            // samples per thread in IIR
#define NPAIR 65            // ceil(129/2) channel pairs
#define KTAIL 48            // LN - NOUT*DSR

__device__ __forceinline__ float2 cmulf(float2 a, float2 b) {
    return make_float2(a.x*b.x - a.y*b.y, a.x*b.y + a.y*b.x);
}

// ---------------- pack real x into complex buffer ----------------
__global__ void pack_x(const float* __restrict__ x, float2* __restrict__ dst) {
    int i = blockIdx.x * 256 + threadIdx.x;
    dst[i] = make_float2(x[i], 0.f);
}

// ---------------- tiled complex transpose (forward path only) ----------------
__global__ void transpose_c(const float2* __restrict__ src, float2* __restrict__ dst,
                            int R, int Cc) {
    __shared__ float2 tile[32][33];
    size_t boff = (size_t)blockIdx.z * LN;
    src += boff; dst += boff;
    int x  = blockIdx.x * 32 + threadIdx.x;
    int y0 = blockIdx.y * 32 + threadIdx.y;
#pragma unroll
    for (int i = 0; i < 32; i += 8)
        tile[threadIdx.y + i][threadIdx.x] = src[(size_t)(y0 + i) * Cc + x];
    __syncthreads();
    int xo  = blockIdx.y * 32 + threadIdx.x;
    int yo0 = blockIdx.x * 32 + threadIdx.y;
#pragma unroll
    for (int i = 0; i < 32; i += 8)
        dst[(size_t)(yo0 + i) * R + xo] = tile[threadIdx.x][threadIdx.y + i];
}

// ---------------- LDS Stockham radix-2 row FFT, natural in/out ----------------
template<int M, int SIGN, int TW>
__global__ __launch_bounds__(256) void fft_rows(const float2* __restrict__ src,
                                                float2* __restrict__ dst,
                                                int rows_per_batch) {
    __shared__ float2 ping[M];
    __shared__ float2 pong[M];
    size_t rowg = blockIdx.x;
    const float2* srow = src + rowg * M;
    float2* drow = dst + rowg * M;
    int row = (int)(rowg % (size_t)rows_per_batch);
    int t = threadIdx.x;
    for (int i = t; i < M; i += 256) ping[i] = srow[i];
    __syncthreads();
    float2* a = ping;
    float2* b = pong;
    for (int Ns = 1; Ns < M; Ns <<= 1) {
        for (int j = t; j < M/2; j += 256) {
            int jm = j & (Ns - 1);
            float2 v0 = a[j];
            float2 v1 = a[j + M/2];
            float ang = (float)SIGN * 3.14159265358979323846f * ((float)jm / (float)Ns);
            float s, c;
            __sincosf(ang, &s, &c);
            float2 w = make_float2(v1.x*c - v1.y*s, v1.x*s + v1.y*c);
            int d0 = ((j & ~(Ns - 1)) << 1) | jm;
            b[d0]      = make_float2(v0.x + w.x, v0.y + w.y);
            b[d0 + Ns] = make_float2(v0.x - w.x, v0.y - w.y);
        }
        __syncthreads();
        float2* tmp = a; a = b; b = tmp;
    }
    if (TW) {
        const float c2pi = 6.28318530717958647692f / (float)LN;
        for (int i = t; i < M; i += 256) {
            float2 v = a[i];
            unsigned prod = ((unsigned)row * (unsigned)i) & (unsigned)(LN - 1);
            float ang = (float)SIGN * c2pi * (float)prod;
            float s, c;
            __sincosf(ang, &s, &c);
            drow[i] = make_float2(v.x*c - v.y*s, v.x*s + v.y*c);
        }
    } else {
        for (int i = t; i < M; i += 256) drow[i] = a[i];
    }
}

// ---------------- Hermitian-combine W[k],W[L-k] from H,X (X real => X[L-k]=conj X[k]) ----
__device__ __forceinline__ void herm2(float2 X1,
                                      float har,  float hai,  float hbr,  float hbi,
                                      float har2, float hai2, float hbr2, float hbi2,
                                      bool hasB, float2& Wk, float2& WkL) {
    float2 a1 = make_float2(har*X1.x - hai*X1.y, har*X1.y + hai*X1.x);
    float2 a2 = make_float2(har2*X1.x + hai2*X1.y, hai2*X1.x - har2*X1.y);
    float yar = 0.5f*(a1.x + a2.x), yai = 0.5f*(a1.y - a2.y);
    float ybr = 0.f, ybi = 0.f;
    if (hasB) {
        float2 b1 = make_float2(hbr*X1.x - hbi*X1.y, hbr*X1.y + hbi*X1.x);
        float2 b2 = make_float2(hbr2*X1.x + hbi2*X1.y, hbi2*X1.x - hbr2*X1.y);
        ybr = 0.5f*(b1.x + b2.x); ybi = 0.5f*(b1.y - b2.y);
    }
    Wk  = make_float2(yar - ybi, yai + ybr);
    WkL = make_float2(yar + ybi, ybr - yai);
}

// ---------------- fused build_w + 512-point column FFT (in-place DIF, sign +1) --------
// Col-major LDS [32 cols][513 rows]: bank = (col + row) mod 32. Butterfly threads are
// lane-fast over the 32 columns -> every stage conflict-free. Twiddles from LDS table.
__global__ __launch_bounds__(1024) void kA(const float* __restrict__ Hr,
                                           const float* __restrict__ Hi,
                                           const float2* __restrict__ X,
                                           float2* __restrict__ D1, int pair0) {
    __shared__ float sRe[32][513];
    __shared__ float sIm[32][513];
    __shared__ float2 twid[512];
    int bb = blockIdx.x;            // column group 0..31
    int pl = blockIdx.y;            // pair within chunk
    int p  = pair0 + pl;
    int ca = 2*p, cb = 2*p + 1;
    bool hasB = (cb < NCH);
    const float* Har = Hr + (size_t)ca * LN;
    const float* Hai = Hi + (size_t)ca * LN;
    const float* Hbr = hasB ? (Hr + (size_t)cb * LN) : Har;
    const float* Hbi = hasB ? (Hi + (size_t)cb * LN) : Hai;
    float2* Dp = D1 + (size_t)pl * LN;
    unsigned c_base = 16u * bb;
    int t = threadIdx.x;

    // ---- twiddle table: twid[h+q] = e^{+i pi q/h}, h=1..256, q<h ----
    if (t >= 512) {
        int idx = t - 512;           // 0..511
        if (idx >= 1) {
            int h = 1 << (31 - __clz((unsigned)idx));
            float ang = 3.14159265358979323846f * (float)(idx - h) / (float)h;
            float s, c; __sincosf(ang, &s, &c);
            twid[idx] = make_float2(c, s);
        }
    }

    // ---- phase 1: Hermitian build of 32 columns into LDS (col-major) ----
#pragma unroll
    for (int i = 0; i < 8; i++) {
        int e = t + (i << 10);
        unsigned c_off = (unsigned)(e & 15);
        unsigned idx   = (unsigned)(e >> 4);        // 0..511
        // 9-bit permutation: keeps wave's 4 r-groups 8 apart (bank-friendly writes)
        unsigned r = (idx & 0x1E0u) | ((idx & 3u) << 3) | ((idx >> 2) & 7u);
        if (bb == 0 && c_off == 0) {
            if (r == 0 || r == 256) {
                unsigned k = 1024u * r;     // bins 0 and L/2
                float2 Xv = X[k];
                float2 a1 = cmulf(make_float2(Har[k], Hai[k]), Xv);
                float br = 0.f;
                if (hasB) { float2 b1 = cmulf(make_float2(Hbr[k], Hbi[k]), Xv); br = b1.x; }
                sRe[0][r] = a1.x; sIm[0][r] = br;
            } else if (r < 256) {
                unsigned k = 1024u * r, kL = 1024u * (512 - r);
                float2 Wk, WkL;
                herm2(X[k], Har[k], Hai[k], Hbr[k], Hbi[k],
                      Har[kL], Hai[kL], Hbr[kL], Hbi[kL], hasB, Wk, WkL);
                sRe[0][r] = Wk.x;        sIm[0][r] = Wk.y;
                sRe[0][512 - r] = WkL.x; sIm[0][512 - r] = WkL.y;
            }
            if (r < 256) {   // col 512 -> slot 16 (self-mirrored rows r <-> 511-r)
                unsigned k = 1024u * r + 512u, kL = 1024u * (511 - r) + 512u;
                float2 Wk, WkL;
                herm2(X[k], Har[k], Hai[k], Hbr[k], Hbi[k],
                      Har[kL], Hai[kL], Hbr[kL], Hbi[kL], hasB, Wk, WkL);
                sRe[16][r] = Wk.x;         sIm[16][r] = Wk.y;
                sRe[16][511 - r] = WkL.x;  sIm[16][511 - r] = WkL.y;
            }
        } else {
            unsigned c = c_base + c_off;
            unsigned k  = 1024u * r + c;
            unsigned kL = 1024u * (511 - r) + (1024u - c);
            float2 Wk, WkL;
            herm2(X[k], Har[k], Hai[k], Hbr[k], Hbi[k],
                  Har[kL], Hai[kL], Hbr[kL], Hbi[kL], hasB, Wk, WkL);
            sRe[c_off][r] = Wk.x;              sIm[c_off][r] = Wk.y;
            sRe[16 + c_off][511 - r] = WkL.x;  sIm[16 + c_off][511 - r] = WkL.y;
        }
    }
    __syncthreads();

    // ---- phase 2: in-place radix-2 DIF 512-FFT (sign +1), lane-fast over columns ----
    int cc   = t & 31;
    int jgrp = t >> 5;               // 0..31
    for (int h = 256; h >= 1; h >>= 1) {
#pragma unroll
        for (int i = 0; i < 8; i++) {
            int j = jgrp + (i << 5);             // 0..255
            int q = j & (h - 1);
            int base = ((j & ~(h - 1)) << 1) | q;
            float2 w = twid[h + q];
            float are = sRe[cc][base],     aim = sIm[cc][base];
            float bre = sRe[cc][base + h], bim = sIm[cc][base + h];
            sRe[cc][base] = are + bre;  sIm[cc][base] = aim + bim;
            float dre = are - bre, dim = aim - bim;
            sRe[cc][base + h] = dre*w.x - dim*w.y;
            sIm[cc][base + h] = dre*w.y + dim*w.x;
        }
        __syncthreads();
    }

    // ---- phase 3: bitrev row, four-step twiddle, coalesced write D1[j][truec] ----
    const float c2pi = 6.28318530717958647692f / (float)LN;
    int slot = t & 31;
    int pos0 = t >> 5;               // 0..31
    unsigned truec = ((unsigned)slot < 16u) ? (c_base + (unsigned)slot)
                   : ((bb == 0 && slot == 16) ? 512u
                                              : (1024u - c_base - (unsigned)(slot - 16)));
#pragma unroll
    for (int i = 0; i < 16; i++) {
        int pos = pos0 + (i << 5);               // 0..511
        unsigned jj = __brev((unsigned)pos) >> 23;   // bitrev9
        float re = sRe[slot][pos], im = sIm[slot][pos];
        unsigned prod = (jj * truec) & (unsigned)(LN - 1);
        float ang = c2pi * (float)prod;
        float s, c;
        __sincosf(ang, &s, &c);
        Dp[(size_t)jj * N2 + truec] = make_float2(re*c - im*s, re*s + im*c);
    }
}

// ---------------- final transpose of IFFT + 1/L scale + power-law ----------------
__global__ void ifft_finish(const float2* __restrict__ src, float* __restrict__ comp,
                            const float* __restrict__ alpha_comp, int pair0) {
    __shared__ float2 tile[32][33];
    int pl = blockIdx.z;
    int p = pair0 + pl;
    int ca = 2*p, cb = 2*p + 1;
    const float2* s = src + (size_t)pl * LN;
    int x  = blockIdx.x * 32 + threadIdx.x;   // col (m) in [0,1024)
    int y0 = blockIdx.y * 32 + threadIdx.y;   // row (j) in [0,512)
#pragma unroll
    for (int i = 0; i < 32; i += 8)
        tile[threadIdx.y + i][threadIdx.x] = s[(size_t)(y0 + i) * N2 + x];
    __syncthreads();
    float aa = alpha_comp[ca];
    float ab = (cb < NCH) ? alpha_comp[cb] : 1.f;
    const float invL = 1.f / (float)LN;
    int xo  = blockIdx.y * 32 + threadIdx.x;  // j
    int yo0 = blockIdx.x * 32 + threadIdx.y;  // m
#pragma unroll
    for (int i = 0; i < 32; i += 8) {
        int yo = yo0 + i;
        float2 v = tile[threadIdx.x][threadIdx.y + i];
        size_t n = (size_t)yo * N1 + xo;      // n = 512*m + j
        float ra = v.x * invL;
        float rb = v.y * invL;
        comp[(size_t)ca * LN + n] = copysignf(powf(fabsf(ra), aa), ra);
        if (cb < NCH)
            comp[(size_t)cb * LN + n] = copysignf(powf(fabsf(rb), ab), rb);
    }
}

// ---------------- leaky IIR part 1: thread-per-20-samples + affine shuffle scan ----------
__global__ __launch_bounds__(256) void iir_part1(
    const float* __restrict__ comp, const float* __restrict__ alpha_leak,
    const float* __restrict__ li_kernel, float* __restrict__ out,
    float* __restrict__ carryOut) {
    __shared__ float win[SPB + SPB/TPW];   // pad every 20 (stride 21)
    __shared__ float wv[4], wg[4];
    int blk = blockIdx.x;
    int c = blockIdx.y;
    int t = threadIdx.x;
    float alpha = alpha_leak[0];
    float k0 = li_kernel[0], k1 = li_kernel[1];
    int base = blk * SPB;
    const int cap = NOUT * DSR;   // 524240
    const float* c0 = comp + (size_t)c * LN;
    const float* c1 = (c + 1 < NCH) ? comp + (size_t)(c + 1) * LN : nullptr;
    for (int i = t; i < SPB; i += 256) {
        int g = base + i;
        float v = 0.f;
        if (g < cap) {
            float u0 = c0[g];
            float u1 = c1 ? c1[g] : 0.f;
            v = fmaxf(k0 * u0 + k1 * u1, 0.f);
        }
        win[i + i / TPW] = v;
    }
    __syncthreads();
    float v = 0.f;
    int lbase = 21 * t;
#pragma unroll
    for (int i = 0; i < TPW; i++)
        v = fmaf(alpha, v, win[lbase + i]);
    float g = powf(alpha, (float)TPW);
    int lid = t & 63, wid = t >> 6;
#pragma unroll
    for (int d = 1; d < 64; d <<= 1) {
        float pv = __shfl_up(v, d);
        float pg = __shfl_up(g, d);
        if (lid >= d) { v = fmaf(g, pv, v); g = g * pg; }
    }
    if (lid == 63) { wv[wid] = v; wg[wid] = g; }
    __syncthreads();
    float cv = 0.f;
#pragma unroll
    for (int w = 0; w < 3; w++)
        if (w < wid) cv = wv[w] + wg[w] * cv;
    float vf = fmaf(g, cv, v);
    int nact = NOUT - blk * OB2; if (nact > OB2) nact = OB2;
    if ((t & 3) == 3) {
        int o = t >> 2;
        if (o < nact)
            out[(size_t)c * NOUT + blk * OB2 + o] = vf;
    }
    if (t == 4 * nact - 1)
        carryOut[c * NBLK + blk] = vf;
}

// ---------------- IIR part 2: per-channel carries (incl. circular wrap) ----------------
__global__ void iir_part2(const float* __restrict__ comp, const float* __restrict__ alpha_leak,
                          const float* __restrict__ li_kernel,
                          const float* __restrict__ carryOut, float* __restrict__ D) {
    int c = threadIdx.x;
    if (c >= NCH) return;
    float alpha = alpha_leak[0];
    float k0 = li_kernel[0], k1 = li_kernel[1];
    const float* c0 = comp + (size_t)c * LN;
    const float* c1 = (c + 1 < NCH) ? comp + (size_t)(c + 1) * LN : nullptr;
    float tail = 0.f, ap = 1.f;
    for (int j = 0; j < KTAIL; j++) {
        int g = LN - 1 - j;
        float u0 = c0[g];
        float u1 = c1 ? c1[g] : 0.f;
        float v = k0 * u0 + k1 * u1; v = v > 0.f ? v : 0.f;
        tail += ap * v;
        ap *= alpha;
    }
    float D0 = tail + ap * carryOut[c * NBLK + (NBLK - 1)]
             + powf(alpha, (float)(KTAIL + 2000)) * carryOut[c * NBLK + (NBLK - 2)];
    D[c * NBLK + 0] = D0;
    for (int b = 1; b < NBLK; b++)
        D[c * NBLK + b] = carryOut[c * NBLK + b - 1];
}

// ---------------- IIR part 3: add decayed carry into each output ----------------
__global__ void iir_part3(const float* __restrict__ D, const float* __restrict__ alpha_leak,
                          float* __restrict__ out) {
    int idx = blockIdx.x * 256 + threadIdx.x;
    if (idx >= NCH * NOUT) return;
    int c = idx / NOUT, m = idx - c * NOUT;
    int b = m / OB2, o = m - b * OB2;
    float alpha = alpha_leak[0];
    float beta = powf(alpha, (float)DSR);
    float dec = powf(beta, (float)(o + 1));
    out[idx] += dec * D[c * NBLK + b];
}

extern "C" void kernel_launch(void* const* d_in, const int* in_sizes, int n_in,
                              void* d_out, int out_size, void* d_ws, size_t ws_size,
                              hipStream_t stream) {
    const float* x  = (const float*)d_in[0];
    const float* Hr = (const float*)d_in[1];
    const float* Hi = (const float*)d_in[2];
    const float* ac = (const float*)d_in[3];
    const float* al = (const float*)d_in[4];
    const float* li = (const float*)d_in[5];
    float* out = (float*)d_out;

    char* ws = (char*)d_ws;
    size_t off = 0;
    auto alloc = [&](size_t bytes) -> void* {
        void* p = ws + off;
        off += (bytes + 255) & ~(size_t)255;
        return p;
    };
    float2* Xf     = (float2*)alloc((size_t)LN * sizeof(float2));
    float*  comp   = (float*) alloc((size_t)NCH * LN * sizeof(float));
    float*  cOut   = (float*) alloc((size_t)NCH * NBLK * sizeof(float));
    float*  Dbuf   = (float*) alloc((size_t)NCH * NBLK * sizeof(float));
    size_t remain = (ws_size > off) ? (ws_size - off) : 0;
    int chunk = (int)(remain / ((size_t)LN * sizeof(float2)));
    if (chunk > NPAIR) chunk = NPAIR;
    if (chunk < 2)     chunk = 2;
    float2* bufB = (float2*)alloc((size_t)chunk * LN * sizeof(float2));

    dim3 tb(32, 8, 1);

    // ---- forward FFT of x (four-step with transposes; small, one signal) ----
    float2* fA = bufB;
    float2* fB = bufB + LN;
    pack_x<<<LN / 256, 256, 0, stream>>>(x, fA);
    transpose_c<<<dim3(N2/32, N1/32, 1), tb, 0, stream>>>(fA, fB, N1, N2);
    fft_rows<N1, -1, 1><<<N2, 256, 0, stream>>>(fB, fB, N2);
    transpose_c<<<dim3(N1/32, N2/32, 1), tb, 0, stream>>>(fB, fA, N2, N1);
    fft_rows<N2, -1, 0><<<N1, 256, 0, stream>>>(fA, fA, N1);
    transpose_c<<<dim3(N2/32, N1/32, 1), tb, 0, stream>>>(fA, Xf, N1, N2);

    // ---- batched inverse FFTs: fused herm-build+colFFT -> rowFFT -> finish ----
    for (int ci = 0; ci < NPAIR; ci += chunk) {
        int np = NPAIR - ci; if (np > chunk) np = chunk;
        kA<<<dim3(32, np), 1024, 0, stream>>>(Hr, Hi, Xf, bufB, ci);
        fft_rows<N2, 1, 0><<<N1 * np, 256, 0, stream>>>(bufB, bufB, N1);
        ifft_finish<<<dim3(N2/32, N1/32, np), tb, 0, stream>>>(bufB, comp, ac, ci);
    }

    // ---- leaky integration (time-domain, exact to fp precision) + downsample ----
    iir_part1<<<dim3(NBLK, NCH, 1), 256, 0, stream>>>(comp, al, li, out, cOut);
    iir_part2<<<1, 256, 0, stream>>>(comp, al, li, cOut, Dbuf);
    iir_part3<<<(NCH * NOUT + 255) / 256, 256, 0, stream>>>(Dbuf, al, out);
}